// Round 10
// baseline (388.140 us; speedup 1.0000x reference)
//
#include <hip/hip_runtime.h>

// WaveletConv2D: 2-level DWT (8-tap), per-position 64x64 channel mix on the
// 4 level-2 subbands, then 2-level inverse DWT. All fp32.
// R11: R10's dwt1 H/V split worked (front kernels ~78us) but aliasing t1 over
// subs+eout evicted eout from L3 -> invfinal's reads went to HBM (FETCH=35.6MB
// = full eout) and its barrier-coupled march went latency-bound (28->98us).
// Single change vs R10: t1 now lives in d_out (dead until invfinal writes it),
// restoring eout L3 residency. Everything else identical.

__constant__ float c_h0[8] = {0.0322231f, -0.01260397f, -0.09921954f, 0.2978578f,
                              0.80373875f, 0.49761867f, -0.02963553f, -0.07576571f};
__constant__ float c_h1[8] = {0.07576571f, -0.02963553f, -0.49761867f, 0.80373875f,
                              -0.2978578f, -0.09921954f, 0.01260397f, 0.0322231f};
// g0 = reverse(h0), g1 = reverse(h1)
__constant__ float c_g0[8] = {-0.07576571f, -0.02963553f, 0.49761867f, 0.80373875f,
                              0.2978578f, -0.09921954f, -0.01260397f, 0.0322231f};
__constant__ float c_g1[8] = {0.0322231f, 0.01260397f, -0.09921954f, -0.2978578f,
                              0.80373875f, -0.49761867f, -0.02963553f, 0.07576571f};

__device__ __forceinline__ float4 f4z() { return make_float4(0.f, 0.f, 0.f, 0.f); }
__device__ __forceinline__ float4 f4fma(float4 a, float w, float4 v) {
  a.x = fmaf(w, v.x, a.x); a.y = fmaf(w, v.y, a.y);
  a.z = fmaf(w, v.z, a.z); a.w = fmaf(w, v.w, a.w);
  return a;
}

// ---- dwt1 pass H: x (32,128,128,64) -> t1 (32,128,64,64), h0 horiz, stride 2 ----
// 16384 blocks, 8 loads + 1 store per thread, no LDS, no barriers.
__global__ __launch_bounds__(256) void k_dwt1h(const float* __restrict__ x,
                                               float* __restrict__ t1) {
  int t = threadIdx.x;
  int c4 = t & 15;
  int owl = t >> 4;                 // 0..15
  int bid = blockIdx.x;             // b*512 + ih*4 + owb
  int owb = bid & 3;
  int ih  = (bid >> 2) & 127;
  int b   = bid >> 9;
  int ow  = owb * 16 + owl;
  const float* row = x + ((size_t)b << 20) + (size_t)ih * 8192 + (c4 << 2);
  int iwbase = 2 * ow - 3;
  float4 v[8];
#pragma unroll
  for (int j = 0; j < 8; ++j) {
    int iw = iwbase + j;
    int iwc = min(max(iw, 0), 127);
    v[j] = *(const float4*)(row + (iwc << 6));
  }
  float4 r = f4z();
#pragma unroll
  for (int j = 0; j < 8; ++j) {
    int iw = iwbase + j;
    float w = ((unsigned)iw < 128u) ? c_h0[j] : 0.f;
    r = f4fma(r, w, v[j]);
  }
  *(float4*)(t1 + ((((size_t)b * 128 + ih) * 64 + ow) << 6) + (c4 << 2)) = r;
}

// ---- dwt1 pass V: t1 (32,128,64,64) -> ll1 (32,64,64,64), h0 vert, stride 2 ----
// 8192 blocks, 8 strided (1KB/wave coalesced) loads + 1 store per thread.
__global__ __launch_bounds__(256) void k_dwt1v(const float* __restrict__ t1,
                                               float* __restrict__ ll1) {
  int t = threadIdx.x;
  int c4 = t & 15;
  int owl = t >> 4;
  int bid = blockIdx.x;             // b*256 + oh*4 + owb
  int owb = bid & 3;
  int oh  = (bid >> 2) & 63;
  int b   = bid >> 8;
  int ow  = owb * 16 + owl;
  const float* col = t1 + ((size_t)b << 19) + ((size_t)ow << 6) + (c4 << 2);
  int ihbase = 2 * oh - 3;
  float4 v[8];
#pragma unroll
  for (int i = 0; i < 8; ++i) {
    int ihc = min(max(ihbase + i, 0), 127);
    v[i] = *(const float4*)(col + ((size_t)ihc << 12));  // ih stride 4096 floats
  }
  float4 r = f4z();
#pragma unroll
  for (int i = 0; i < 8; ++i) {
    int ihh = ihbase + i;
    float w = ((unsigned)ihh < 128u) ? c_h0[i] : 0.f;
    r = f4fma(r, w, v[i]);
  }
  *(float4*)(ll1 + ((((size_t)b * 64 + oh) * 64 + ow) << 6) + (c4 << 2)) = r;
}

// ---- Weight transpose: W[i,o,hw] (4096 x 1024) -> Wt[hw][io], 64x64 f4 tiles ----
__global__ __launch_bounds__(256) void k_transpose(const float* __restrict__ w1,
                                                   const float* __restrict__ w2,
                                                   const float* __restrict__ w3,
                                                   const float* __restrict__ w4,
                                                   float* __restrict__ wt) {
  __shared__ float tile[64 * 65];       // 16640 B
  int t = threadIdx.x;
  int bid = blockIdx.x;
  int s   = bid >> 10;                  // 0..3
  int rem = bid & 1023;
  int hw0 = (rem & 15) << 6;            // 16 hw-tiles
  int io0 = (rem >> 4) << 6;            // 64 io-tiles
  const float* w = (s == 0) ? w1 : (s == 1) ? w2 : (s == 2) ? w3 : w4;
  int c = t & 15;                       // hw float4 lane
  int r = t >> 4;                       // 0..15
#pragma unroll
  for (int k = 0; k < 4; ++k) {
    int io = r + 16 * k;                // io_local 0..63
    float4 v = *(const float4*)(w + (size_t)(io0 + io) * 1024 + hw0 + c * 4);
    tile[io * 65 + c * 4 + 0] = v.x;
    tile[io * 65 + c * 4 + 1] = v.y;
    tile[io * 65 + c * 4 + 2] = v.z;
    tile[io * 65 + c * 4 + 3] = v.w;
  }
  __syncthreads();
  float* o = wt + (size_t)s * 4194304;
#pragma unroll
  for (int k = 0; k < 4; ++k) {
    int hr = r + 16 * k;                // hw_local 0..63
    float4 v;
    v.x = tile[(c * 4 + 0) * 65 + hr];
    v.y = tile[(c * 4 + 1) * 65 + hr];
    v.z = tile[(c * 4 + 2) * 65 + hr];
    v.w = tile[(c * 4 + 3) * 65 + hr];
    *(float4*)(o + (size_t)(hw0 + hr) * 4096 + io0 + c * 4) = v;
  }
}

// ---- Stage 2: ll1 (32,64,64,64) -> 4 subbands (32,32,32,64) ----
__global__ __launch_bounds__(256) void k_dwt2(const float* __restrict__ ll1,
                                              float* __restrict__ subs) {
  __shared__ float4 sRow[2][40 * 17];
  int t = threadIdx.x;
  int c4 = t & 15;
  int owl = t >> 4;
  int bid = blockIdx.x;             // b*16 + ohc*2 + owb
  int owb = bid & 1;
  int ohc = (bid >> 1) & 7;
  int b   = bid >> 4;
  int ow0 = owb * 16;
  int ow  = ow0 + owl;
  int oh0 = ohc * 4;
  int iw_start = 2 * ow0 - 3;
  const float* lb = ll1 + ((size_t)b << 18);

  auto stage2 = [&](int ih0) {
#pragma unroll
    for (int base = 0; base < 80; base += 16) {
      int item = base + owl;
      int rw   = item >= 40 ? 1 : 0;
      int iw_s = item - rw * 40;
      int ihc  = min(max(ih0 + rw, 0), 63);
      int iwc  = min(max(iw_start + iw_s, 0), 63);
      sRow[rw][iw_s * 17 + c4] =
          *(const float4*)(lb + (size_t)ihc * 4096 + (iwc << 6) + (c4 << 2));
    }
  };

  auto hrow2L = [&](int rw, int ih, float4& rl, float4& rh) {
    rl = f4z(); rh = f4z();
    if ((unsigned)ih >= 64u) return;
#pragma unroll
    for (int j = 0; j < 8; ++j) {
      int iw  = 2 * ow - 3 + j;
      int iwc = min(max(iw, 0), 63);
      int iw_s = iwc - iw_start;
      bool ok = (unsigned)iw < 64u;
      float wl = ok ? c_h0[j] : 0.f;
      float wh = ok ? c_h1[j] : 0.f;
      float4 v = sRow[rw][iw_s * 17 + c4];
      rl = f4fma(rl, wl, v);
      rh = f4fma(rh, wh, v);
    }
  };

  float4 Rl[8], Rh[8];
  int ihb = 2 * oh0 - 3;
#pragma unroll
  for (int pk = 0; pk < 3; ++pk) {
    stage2(ihb + 2 * pk);
    __syncthreads();
    hrow2L(0, ihb + 2 * pk,     Rl[2 * pk],     Rh[2 * pk]);
    hrow2L(1, ihb + 2 * pk + 1, Rl[2 * pk + 1], Rh[2 * pk + 1]);
    __syncthreads();
  }
  float* outp = subs + ((((size_t)b * 32 + oh0) * 32 + ow) << 6) + (c4 << 2);
#pragma unroll
  for (int oo = 0; oo < 4; ++oo) {
    stage2(ihb + 6);
    __syncthreads();
    hrow2L(0, ihb + 6, Rl[6], Rh[6]);
    hrow2L(1, ihb + 7, Rl[7], Rh[7]);
    float4 a_ll = f4z(), a_lh = f4z(), a_hl = f4z(), a_hh = f4z();
#pragma unroll
    for (int i = 0; i < 8; ++i) {
      a_ll = f4fma(a_ll, c_h0[i], Rl[i]);
      a_lh = f4fma(a_lh, c_h0[i], Rh[i]);
      a_hl = f4fma(a_hl, c_h1[i], Rl[i]);
      a_hh = f4fma(a_hh, c_h1[i], Rh[i]);
    }
    float* o = outp + oo * 2048;
    *(float4*)(o)           = a_ll;
    *(float4*)(o + 2097152) = a_lh;
    *(float4*)(o + 4194304) = a_hl;
    *(float4*)(o + 6291456) = a_hh;
    __syncthreads();
#pragma unroll
    for (int k = 0; k < 6; ++k) { Rl[k] = Rl[k + 2]; Rh[k] = Rh[k + 2]; }
    ihb += 2;
  }
}

// ---- Einsum: out[b,p,o] = sum_i A[b,p,i] * W[i,o,p], per spatial position p ----
__global__ __launch_bounds__(256) void k_einsum(const float* __restrict__ subs,
                                               const float* __restrict__ w1,
                                               const float* __restrict__ w2,
                                               const float* __restrict__ w3,
                                               const float* __restrict__ w4,
                                               const float* __restrict__ wt,
                                               float* __restrict__ eout,
                                               int use_wt) {
  __shared__ float sW[4096];  // [i][o]
  __shared__ float sA[2048];  // [b][i]
  int p = blockIdx.x;   // 0..1023 = h*32+w
  int s = blockIdx.y;   // subband
  int t = threadIdx.x;
  const float* A = subs + (size_t)s * 2097152;
  if (use_wt) {
    const float* Wp = wt + (size_t)s * 4194304 + (size_t)p * 4096;
#pragma unroll
    for (int k = 0; k < 16; ++k) sW[t + 256 * k] = Wp[t + 256 * k];
  } else {
    const float* Ws = (s == 0) ? w1 : (s == 1) ? w2 : (s == 2) ? w3 : w4;
#pragma unroll
    for (int k = 0; k < 16; ++k) {
      int e = t + 256 * k;
      sW[e] = Ws[e * 1024 + p];
    }
  }
#pragma unroll
  for (int k = 0; k < 8; ++k) {
    int e = t + 256 * k;                       // e = b*64 + i
    sA[e] = A[(e >> 6) * 65536 + (p << 6) + (e & 63)];
  }
  __syncthreads();
  int o  = t & 63;
  int bg = t >> 6;  // 0..3, handles b = bg*8 .. bg*8+7
  float acc[8] = {0.f, 0.f, 0.f, 0.f, 0.f, 0.f, 0.f, 0.f};
  for (int i = 0; i < 64; ++i) {
    float wv = sW[(i << 6) + o];
#pragma unroll
    for (int k = 0; k < 8; ++k) acc[k] += sA[((bg * 8 + k) << 6) + i] * wv;
  }
  float* Oo = eout + (size_t)s * 2097152 + (p << 6) + o;
#pragma unroll
  for (int k = 0; k < 8; ++k) Oo[(bg * 8 + k) * 65536] = acc[k];
}

// ---- Fused inverse: 4 subbands eout (32,32,32,64) -> out (32,128,128,64) ----
__global__ __launch_bounds__(256) void k_invfinal(const float* __restrict__ eout,
                                                  float* __restrict__ out) {
  __shared__ float4 sRes[3][2][20][16];   // 30720 B
  int t = threadIdx.x;
  int c4 = t & 15;
  int ql = t >> 4;                  // 0..15
  int bid = blockIdx.x;             // b*16 + yt*4 + xt
  int xt = bid & 3;
  int yt = (bid >> 2) & 3;
  int b  = bid >> 4;
  int q0 = xt * 16;                 // final-q base (out cols 2q0..2q0+31)
  int qi0 = (q0 >> 1) - 1;          // invres-q base (10 slots)
  int qi = qi0 + ql;                // valid work for ql < 10
  int r0p = yt * 8;                 // first emitted res-pair index

  auto loadrowI = [&](int m, float4& ae, float4& ao, float4& be, float4& bo) {
    ae = f4z(); ao = f4z(); be = f4z(); bo = f4z();
    if ((unsigned)m >= 32u) return;
    const float* base = eout + ((((size_t)b * 32 + m) * 32) << 6) + (c4 << 2);
    float4 vf[4], vl[4], vh[4], vv[4];
#pragma unroll
    for (int dn = -1; dn <= 2; ++dn) {
      int n = qi + dn;
      int nc = min(max(n, 0), 31);
      const float* p = base + (nc << 6);
      vf[dn + 1] = *(const float4*)(p);
      vl[dn + 1] = *(const float4*)(p + 2097152);
      vh[dn + 1] = *(const float4*)(p + 4194304);
      vv[dn + 1] = *(const float4*)(p + 6291456);
    }
#pragma unroll
    for (int dn = -1; dn <= 2; ++dn) {
      int n = qi + dn;
      bool ok = (unsigned)n < 32u;
      float g0e = ok ? c_g0[2 * dn + 3] : 0.f, g1e = ok ? c_g1[2 * dn + 3] : 0.f;
      float g0o = ok ? c_g0[2 * dn + 2] : 0.f, g1o = ok ? c_g1[2 * dn + 2] : 0.f;
      ae = f4fma(ae, g0e, vf[dn + 1]); ae = f4fma(ae, g1e, vl[dn + 1]);
      ao = f4fma(ao, g0o, vf[dn + 1]); ao = f4fma(ao, g1o, vl[dn + 1]);
      be = f4fma(be, g0e, vh[dn + 1]); be = f4fma(be, g1e, vv[dn + 1]);
      bo = f4fma(bo, g0o, vh[dn + 1]); bo = f4fma(bo, g1o, vv[dn + 1]);
    }
  };

  float4 Ae[4], Ao[4], Be[4], Bo[4];
  int prs = r0p - 1;                // pair cursor

  auto steppair = [&]() {
    loadrowI(prs + 2, Ae[3], Ao[3], Be[3], Bo[3]);
    float4 ee = f4z(), eo = f4z(), oe = f4z(), oo = f4z();
    if ((unsigned)prs < 32u) {
#pragma unroll
      for (int dm = 0; dm < 4; ++dm) {
        float gye = c_g0[2 * dm + 1], hye = c_g1[2 * dm + 1];
        float gyo = c_g0[2 * dm],     hyo = c_g1[2 * dm];
        ee = f4fma(ee, gye, Ae[dm]); ee = f4fma(ee, hye, Be[dm]);
        eo = f4fma(eo, gye, Ao[dm]); eo = f4fma(eo, hye, Bo[dm]);
        oe = f4fma(oe, gyo, Ae[dm]); oe = f4fma(oe, hyo, Be[dm]);
        oo = f4fma(oo, gyo, Ao[dm]); oo = f4fma(oo, hyo, Bo[dm]);
      }
    }
    int slot = ((prs % 3) + 3) % 3;
    sRes[slot][0][2 * ql][c4]     = ee;
    sRes[slot][0][2 * ql + 1][c4] = eo;
    sRes[slot][1][2 * ql][c4]     = oe;
    sRes[slot][1][2 * ql + 1][c4] = oo;
#pragma unroll
    for (int k = 0; k < 3; ++k) {
      Ae[k] = Ae[k + 1]; Ao[k] = Ao[k + 1]; Be[k] = Be[k + 1]; Bo[k] = Bo[k + 1];
    }
  };

  if (ql < 10) {
    loadrowI(prs - 1, Ae[0], Ao[0], Be[0], Bo[0]);
    loadrowI(prs,     Ae[1], Ao[1], Be[1], Bo[1]);
    loadrowI(prs + 1, Ae[2], Ao[2], Be[2], Bo[2]);
  }
#pragma unroll
  for (int pk = 0; pk < 2; ++pk) {
    if (ql < 10) steppair();
    ++prs;
  }
  int q = q0 + ql;
#pragma unroll
  for (int it = 0; it < 8; ++it) {
    if (ql < 10) steppair();       // computes pair prs
    __syncthreads();
    float4 H0[5], H1[5];
#pragma unroll
    for (int mi = 0; mi < 5; ++mi) {
      int m = 2 * (prs - 1) - 1 + mi;  // res row
      int pm = m >> 1;
      int ey = m & 1;
      int slot = ((pm % 3) + 3) % 3;
      float4 h0v = f4z(), h1v = f4z();
#pragma unroll
      for (int dn = -1; dn <= 2; ++dn) {
        int n = q + dn;
        bool ok = (unsigned)n < 64u;
        float we = ok ? c_g0[2 * dn + 3] : 0.f;
        float wo = ok ? c_g0[2 * dn + 2] : 0.f;
        float4 v = sRes[slot][ey][ql + 2 + dn][c4];
        h0v = f4fma(h0v, we, v);
        h1v = f4fma(h1v, wo, v);
      }
      H0[mi] = h0v; H1[mi] = h1v;
    }
#pragma unroll
    for (int rr2 = 0; rr2 < 2; ++rr2) {
      int r = 2 * (prs - 1) + rr2;
      float4 aee = f4z(), aeo = f4z(), aoe = f4z(), aoo = f4z();
#pragma unroll
      for (int dm = 0; dm < 4; ++dm) {
        float gye = c_g0[2 * dm + 1];
        float gyo = c_g0[2 * dm];
        aee = f4fma(aee, gye, H0[rr2 + dm]);
        aeo = f4fma(aeo, gye, H1[rr2 + dm]);
        aoe = f4fma(aoe, gyo, H0[rr2 + dm]);
        aoo = f4fma(aoo, gyo, H1[rr2 + dm]);
      }
      int y = 2 * r, xx = 2 * q;
      float* ob = out + (((size_t)(b * 128 + y)) * 128 + xx) * 64 + (c4 << 2);
      *(float4*)(ob)              = aee;
      *(float4*)(ob + 64)         = aeo;
      *(float4*)(ob + 8192)       = aoe;
      *(float4*)(ob + 8192 + 64)  = aoo;
    }
    __syncthreads();
    ++prs;
  }
}

extern "C" void kernel_launch(void* const* d_in, const int* in_sizes, int n_in,
                              void* d_out, int out_size, void* d_ws, size_t ws_size,
                              hipStream_t stream) {
  (void)in_sizes; (void)n_in; (void)out_size;
  const float* x  = (const float*)d_in[0];
  const float* w1 = (const float*)d_in[1];
  const float* w2 = (const float*)d_in[2];
  const float* w3 = (const float*)d_in[3];
  const float* w4 = (const float*)d_in[4];
  float* out = (float*)d_out;
  float* ws  = (float*)d_ws;

  // Workspace layout (floats):
  //   [0,        8388608)  ll1
  //   [8388608, 16777216)  subs (4 x 2097152)
  //   [16777216,25165824)  eout (4 x 2097152)
  //   [25165824,41943040)  wt (4 x 4194304), optional
  // t1 (dwt1 intermediate, 16.8M floats = 64MB) lives in d_out (128MB):
  // dead from kernel_launch start until k_invfinal overwrites out.
  float* ll1  = ws;
  float* subs = ws + 8388608;
  float* eout = ws + 16777216;
  float* wt   = ws + 25165824;
  float* t1   = out;
  int use_wt = (ws_size >= (size_t)41943040 * 4) ? 1 : 0;

  k_dwt1h<<<16384, 256, 0, stream>>>(x, t1);
  if (use_wt) k_transpose<<<4096, 256, 0, stream>>>(w1, w2, w3, w4, wt);
  k_dwt1v<<<8192, 256, 0, stream>>>(t1, ll1);
  k_dwt2<<<512, 256, 0, stream>>>(ll1, subs);
  k_einsum<<<dim3(1024, 4), 256, 0, stream>>>(subs, w1, w2, w3, w4, wt, eout, use_wt);
  k_invfinal<<<512, 256, 0, stream>>>(eout, out);
}

// Round 11
// 380.973 us; speedup vs baseline: 1.0188x; 1.0188x over previous
//
#include <hip/hip_runtime.h>

// WaveletConv2D: 2-level DWT (8-tap), per-position 64x64 channel mix on the
// 4 level-2 subbands, then 2-level inverse DWT. All fp32.
// R12: R10 (t1 over subs/eout) and R11 (t1 over out) both cost 388 -- t1's
// 67MB dirties whichever hot region it lands in (R10: evicts eout -> invfinal
// FETCH=35.6MB, 98us; R11: dirties out -> front half pays). Fix: overlay t1 on
// the wt region (exact 16.8M-float fit) and reorder: dwt1h -> dwt1v ->
// transpose (overwrites dead t1) -> dwt2 -> einsum -> invfinal. subs/eout/out
// now see the same cache pattern as R8/R9 where invfinal ran ~25us.

__constant__ float c_h0[8] = {0.0322231f, -0.01260397f, -0.09921954f, 0.2978578f,
                              0.80373875f, 0.49761867f, -0.02963553f, -0.07576571f};
__constant__ float c_h1[8] = {0.07576571f, -0.02963553f, -0.49761867f, 0.80373875f,
                              -0.2978578f, -0.09921954f, 0.01260397f, 0.0322231f};
// g0 = reverse(h0), g1 = reverse(h1)
__constant__ float c_g0[8] = {-0.07576571f, -0.02963553f, 0.49761867f, 0.80373875f,
                              0.2978578f, -0.09921954f, -0.01260397f, 0.0322231f};
__constant__ float c_g1[8] = {0.0322231f, 0.01260397f, -0.09921954f, -0.2978578f,
                              0.80373875f, -0.49761867f, -0.02963553f, 0.07576571f};

__device__ __forceinline__ float4 f4z() { return make_float4(0.f, 0.f, 0.f, 0.f); }
__device__ __forceinline__ float4 f4fma(float4 a, float w, float4 v) {
  a.x = fmaf(w, v.x, a.x); a.y = fmaf(w, v.y, a.y);
  a.z = fmaf(w, v.z, a.z); a.w = fmaf(w, v.w, a.w);
  return a;
}

// ---- dwt1 pass H: x (32,128,128,64) -> t1 (32,128,64,64), h0 horiz, stride 2 ----
__global__ __launch_bounds__(256) void k_dwt1h(const float* __restrict__ x,
                                               float* __restrict__ t1) {
  int t = threadIdx.x;
  int c4 = t & 15;
  int owl = t >> 4;                 // 0..15
  int bid = blockIdx.x;             // b*512 + ih*4 + owb
  int owb = bid & 3;
  int ih  = (bid >> 2) & 127;
  int b   = bid >> 9;
  int ow  = owb * 16 + owl;
  const float* row = x + ((size_t)b << 20) + (size_t)ih * 8192 + (c4 << 2);
  int iwbase = 2 * ow - 3;
  float4 v[8];
#pragma unroll
  for (int j = 0; j < 8; ++j) {
    int iw = iwbase + j;
    int iwc = min(max(iw, 0), 127);
    v[j] = *(const float4*)(row + (iwc << 6));
  }
  float4 r = f4z();
#pragma unroll
  for (int j = 0; j < 8; ++j) {
    int iw = iwbase + j;
    float w = ((unsigned)iw < 128u) ? c_h0[j] : 0.f;
    r = f4fma(r, w, v[j]);
  }
  *(float4*)(t1 + ((((size_t)b * 128 + ih) * 64 + ow) << 6) + (c4 << 2)) = r;
}

// ---- dwt1 pass V: t1 (32,128,64,64) -> ll1 (32,64,64,64), h0 vert, stride 2 ----
__global__ __launch_bounds__(256) void k_dwt1v(const float* __restrict__ t1,
                                               float* __restrict__ ll1) {
  int t = threadIdx.x;
  int c4 = t & 15;
  int owl = t >> 4;
  int bid = blockIdx.x;             // b*256 + oh*4 + owb
  int owb = bid & 3;
  int oh  = (bid >> 2) & 63;
  int b   = bid >> 8;
  int ow  = owb * 16 + owl;
  const float* col = t1 + ((size_t)b << 19) + ((size_t)ow << 6) + (c4 << 2);
  int ihbase = 2 * oh - 3;
  float4 v[8];
#pragma unroll
  for (int i = 0; i < 8; ++i) {
    int ihc = min(max(ihbase + i, 0), 127);
    v[i] = *(const float4*)(col + ((size_t)ihc << 12));  // ih stride 4096 floats
  }
  float4 r = f4z();
#pragma unroll
  for (int i = 0; i < 8; ++i) {
    int ihh = ihbase + i;
    float w = ((unsigned)ihh < 128u) ? c_h0[i] : 0.f;
    r = f4fma(r, w, v[i]);
  }
  *(float4*)(ll1 + ((((size_t)b * 64 + oh) * 64 + ow) << 6) + (c4 << 2)) = r;
}

// ---- Weight transpose: W[i,o,hw] (4096 x 1024) -> Wt[hw][io], 64x64 f4 tiles ----
__global__ __launch_bounds__(256) void k_transpose(const float* __restrict__ w1,
                                                   const float* __restrict__ w2,
                                                   const float* __restrict__ w3,
                                                   const float* __restrict__ w4,
                                                   float* __restrict__ wt) {
  __shared__ float tile[64 * 65];       // 16640 B
  int t = threadIdx.x;
  int bid = blockIdx.x;
  int s   = bid >> 10;                  // 0..3
  int rem = bid & 1023;
  int hw0 = (rem & 15) << 6;            // 16 hw-tiles
  int io0 = (rem >> 4) << 6;            // 64 io-tiles
  const float* w = (s == 0) ? w1 : (s == 1) ? w2 : (s == 2) ? w3 : w4;
  int c = t & 15;                       // hw float4 lane
  int r = t >> 4;                       // 0..15
#pragma unroll
  for (int k = 0; k < 4; ++k) {
    int io = r + 16 * k;                // io_local 0..63
    float4 v = *(const float4*)(w + (size_t)(io0 + io) * 1024 + hw0 + c * 4);
    tile[io * 65 + c * 4 + 0] = v.x;
    tile[io * 65 + c * 4 + 1] = v.y;
    tile[io * 65 + c * 4 + 2] = v.z;
    tile[io * 65 + c * 4 + 3] = v.w;
  }
  __syncthreads();
  float* o = wt + (size_t)s * 4194304;
#pragma unroll
  for (int k = 0; k < 4; ++k) {
    int hr = r + 16 * k;                // hw_local 0..63
    float4 v;
    v.x = tile[(c * 4 + 0) * 65 + hr];
    v.y = tile[(c * 4 + 1) * 65 + hr];
    v.z = tile[(c * 4 + 2) * 65 + hr];
    v.w = tile[(c * 4 + 3) * 65 + hr];
    *(float4*)(o + (size_t)(hw0 + hr) * 4096 + io0 + c * 4) = v;
  }
}

// ---- Stage 2: ll1 (32,64,64,64) -> 4 subbands (32,32,32,64) ----
__global__ __launch_bounds__(256) void k_dwt2(const float* __restrict__ ll1,
                                              float* __restrict__ subs) {
  __shared__ float4 sRow[2][40 * 17];
  int t = threadIdx.x;
  int c4 = t & 15;
  int owl = t >> 4;
  int bid = blockIdx.x;             // b*16 + ohc*2 + owb
  int owb = bid & 1;
  int ohc = (bid >> 1) & 7;
  int b   = bid >> 4;
  int ow0 = owb * 16;
  int ow  = ow0 + owl;
  int oh0 = ohc * 4;
  int iw_start = 2 * ow0 - 3;
  const float* lb = ll1 + ((size_t)b << 18);

  auto stage2 = [&](int ih0) {
#pragma unroll
    for (int base = 0; base < 80; base += 16) {
      int item = base + owl;
      int rw   = item >= 40 ? 1 : 0;
      int iw_s = item - rw * 40;
      int ihc  = min(max(ih0 + rw, 0), 63);
      int iwc  = min(max(iw_start + iw_s, 0), 63);
      sRow[rw][iw_s * 17 + c4] =
          *(const float4*)(lb + (size_t)ihc * 4096 + (iwc << 6) + (c4 << 2));
    }
  };

  auto hrow2L = [&](int rw, int ih, float4& rl, float4& rh) {
    rl = f4z(); rh = f4z();
    if ((unsigned)ih >= 64u) return;
#pragma unroll
    for (int j = 0; j < 8; ++j) {
      int iw  = 2 * ow - 3 + j;
      int iwc = min(max(iw, 0), 63);
      int iw_s = iwc - iw_start;
      bool ok = (unsigned)iw < 64u;
      float wl = ok ? c_h0[j] : 0.f;
      float wh = ok ? c_h1[j] : 0.f;
      float4 v = sRow[rw][iw_s * 17 + c4];
      rl = f4fma(rl, wl, v);
      rh = f4fma(rh, wh, v);
    }
  };

  float4 Rl[8], Rh[8];
  int ihb = 2 * oh0 - 3;
#pragma unroll
  for (int pk = 0; pk < 3; ++pk) {
    stage2(ihb + 2 * pk);
    __syncthreads();
    hrow2L(0, ihb + 2 * pk,     Rl[2 * pk],     Rh[2 * pk]);
    hrow2L(1, ihb + 2 * pk + 1, Rl[2 * pk + 1], Rh[2 * pk + 1]);
    __syncthreads();
  }
  float* outp = subs + ((((size_t)b * 32 + oh0) * 32 + ow) << 6) + (c4 << 2);
#pragma unroll
  for (int oo = 0; oo < 4; ++oo) {
    stage2(ihb + 6);
    __syncthreads();
    hrow2L(0, ihb + 6, Rl[6], Rh[6]);
    hrow2L(1, ihb + 7, Rl[7], Rh[7]);
    float4 a_ll = f4z(), a_lh = f4z(), a_hl = f4z(), a_hh = f4z();
#pragma unroll
    for (int i = 0; i < 8; ++i) {
      a_ll = f4fma(a_ll, c_h0[i], Rl[i]);
      a_lh = f4fma(a_lh, c_h0[i], Rh[i]);
      a_hl = f4fma(a_hl, c_h1[i], Rl[i]);
      a_hh = f4fma(a_hh, c_h1[i], Rh[i]);
    }
    float* o = outp + oo * 2048;
    *(float4*)(o)           = a_ll;
    *(float4*)(o + 2097152) = a_lh;
    *(float4*)(o + 4194304) = a_hl;
    *(float4*)(o + 6291456) = a_hh;
    __syncthreads();
#pragma unroll
    for (int k = 0; k < 6; ++k) { Rl[k] = Rl[k + 2]; Rh[k] = Rh[k + 2]; }
    ihb += 2;
  }
}

// ---- Einsum: out[b,p,o] = sum_i A[b,p,i] * W[i,o,p], per spatial position p ----
__global__ __launch_bounds__(256) void k_einsum(const float* __restrict__ subs,
                                               const float* __restrict__ w1,
                                               const float* __restrict__ w2,
                                               const float* __restrict__ w3,
                                               const float* __restrict__ w4,
                                               const float* __restrict__ wt,
                                               float* __restrict__ eout,
                                               int use_wt) {
  __shared__ float sW[4096];  // [i][o]
  __shared__ float sA[2048];  // [b][i]
  int p = blockIdx.x;   // 0..1023 = h*32+w
  int s = blockIdx.y;   // subband
  int t = threadIdx.x;
  const float* A = subs + (size_t)s * 2097152;
  if (use_wt) {
    const float* Wp = wt + (size_t)s * 4194304 + (size_t)p * 4096;
#pragma unroll
    for (int k = 0; k < 16; ++k) sW[t + 256 * k] = Wp[t + 256 * k];
  } else {
    const float* Ws = (s == 0) ? w1 : (s == 1) ? w2 : (s == 2) ? w3 : w4;
#pragma unroll
    for (int k = 0; k < 16; ++k) {
      int e = t + 256 * k;
      sW[e] = Ws[e * 1024 + p];
    }
  }
#pragma unroll
  for (int k = 0; k < 8; ++k) {
    int e = t + 256 * k;                       // e = b*64 + i
    sA[e] = A[(e >> 6) * 65536 + (p << 6) + (e & 63)];
  }
  __syncthreads();
  int o  = t & 63;
  int bg = t >> 6;  // 0..3, handles b = bg*8 .. bg*8+7
  float acc[8] = {0.f, 0.f, 0.f, 0.f, 0.f, 0.f, 0.f, 0.f};
  for (int i = 0; i < 64; ++i) {
    float wv = sW[(i << 6) + o];
#pragma unroll
    for (int k = 0; k < 8; ++k) acc[k] += sA[((bg * 8 + k) << 6) + i] * wv;
  }
  float* Oo = eout + (size_t)s * 2097152 + (p << 6) + o;
#pragma unroll
  for (int k = 0; k < 8; ++k) Oo[(bg * 8 + k) * 65536] = acc[k];
}

// ---- Fused inverse: 4 subbands eout (32,32,32,64) -> out (32,128,128,64) ----
__global__ __launch_bounds__(256) void k_invfinal(const float* __restrict__ eout,
                                                  float* __restrict__ out) {
  __shared__ float4 sRes[3][2][20][16];   // 30720 B
  int t = threadIdx.x;
  int c4 = t & 15;
  int ql = t >> 4;                  // 0..15
  int bid = blockIdx.x;             // b*16 + yt*4 + xt
  int xt = bid & 3;
  int yt = (bid >> 2) & 3;
  int b  = bid >> 4;
  int q0 = xt * 16;                 // final-q base (out cols 2q0..2q0+31)
  int qi0 = (q0 >> 1) - 1;          // invres-q base (10 slots)
  int qi = qi0 + ql;                // valid work for ql < 10
  int r0p = yt * 8;                 // first emitted res-pair index

  auto loadrowI = [&](int m, float4& ae, float4& ao, float4& be, float4& bo) {
    ae = f4z(); ao = f4z(); be = f4z(); bo = f4z();
    if ((unsigned)m >= 32u) return;
    const float* base = eout + ((((size_t)b * 32 + m) * 32) << 6) + (c4 << 2);
    float4 vf[4], vl[4], vh[4], vv[4];
#pragma unroll
    for (int dn = -1; dn <= 2; ++dn) {
      int n = qi + dn;
      int nc = min(max(n, 0), 31);
      const float* p = base + (nc << 6);
      vf[dn + 1] = *(const float4*)(p);
      vl[dn + 1] = *(const float4*)(p + 2097152);
      vh[dn + 1] = *(const float4*)(p + 4194304);
      vv[dn + 1] = *(const float4*)(p + 6291456);
    }
#pragma unroll
    for (int dn = -1; dn <= 2; ++dn) {
      int n = qi + dn;
      bool ok = (unsigned)n < 32u;
      float g0e = ok ? c_g0[2 * dn + 3] : 0.f, g1e = ok ? c_g1[2 * dn + 3] : 0.f;
      float g0o = ok ? c_g0[2 * dn + 2] : 0.f, g1o = ok ? c_g1[2 * dn + 2] : 0.f;
      ae = f4fma(ae, g0e, vf[dn + 1]); ae = f4fma(ae, g1e, vl[dn + 1]);
      ao = f4fma(ao, g0o, vf[dn + 1]); ao = f4fma(ao, g1o, vl[dn + 1]);
      be = f4fma(be, g0e, vh[dn + 1]); be = f4fma(be, g1e, vv[dn + 1]);
      bo = f4fma(bo, g0o, vh[dn + 1]); bo = f4fma(bo, g1o, vv[dn + 1]);
    }
  };

  float4 Ae[4], Ao[4], Be[4], Bo[4];
  int prs = r0p - 1;                // pair cursor

  auto steppair = [&]() {
    loadrowI(prs + 2, Ae[3], Ao[3], Be[3], Bo[3]);
    float4 ee = f4z(), eo = f4z(), oe = f4z(), oo = f4z();
    if ((unsigned)prs < 32u) {
#pragma unroll
      for (int dm = 0; dm < 4; ++dm) {
        float gye = c_g0[2 * dm + 1], hye = c_g1[2 * dm + 1];
        float gyo = c_g0[2 * dm],     hyo = c_g1[2 * dm];
        ee = f4fma(ee, gye, Ae[dm]); ee = f4fma(ee, hye, Be[dm]);
        eo = f4fma(eo, gye, Ao[dm]); eo = f4fma(eo, hye, Bo[dm]);
        oe = f4fma(oe, gyo, Ae[dm]); oe = f4fma(oe, hyo, Be[dm]);
        oo = f4fma(oo, gyo, Ao[dm]); oo = f4fma(oo, hyo, Bo[dm]);
      }
    }
    int slot = ((prs % 3) + 3) % 3;
    sRes[slot][0][2 * ql][c4]     = ee;
    sRes[slot][0][2 * ql + 1][c4] = eo;
    sRes[slot][1][2 * ql][c4]     = oe;
    sRes[slot][1][2 * ql + 1][c4] = oo;
#pragma unroll
    for (int k = 0; k < 3; ++k) {
      Ae[k] = Ae[k + 1]; Ao[k] = Ao[k + 1]; Be[k] = Be[k + 1]; Bo[k] = Bo[k + 1];
    }
  };

  if (ql < 10) {
    loadrowI(prs - 1, Ae[0], Ao[0], Be[0], Bo[0]);
    loadrowI(prs,     Ae[1], Ao[1], Be[1], Bo[1]);
    loadrowI(prs + 1, Ae[2], Ao[2], Be[2], Bo[2]);
  }
#pragma unroll
  for (int pk = 0; pk < 2; ++pk) {
    if (ql < 10) steppair();
    ++prs;
  }
  int q = q0 + ql;
#pragma unroll
  for (int it = 0; it < 8; ++it) {
    if (ql < 10) steppair();       // computes pair prs
    __syncthreads();
    float4 H0[5], H1[5];
#pragma unroll
    for (int mi = 0; mi < 5; ++mi) {
      int m = 2 * (prs - 1) - 1 + mi;  // res row
      int pm = m >> 1;
      int ey = m & 1;
      int slot = ((pm % 3) + 3) % 3;
      float4 h0v = f4z(), h1v = f4z();
#pragma unroll
      for (int dn = -1; dn <= 2; ++dn) {
        int n = q + dn;
        bool ok = (unsigned)n < 64u;
        float we = ok ? c_g0[2 * dn + 3] : 0.f;
        float wo = ok ? c_g0[2 * dn + 2] : 0.f;
        float4 v = sRes[slot][ey][ql + 2 + dn][c4];
        h0v = f4fma(h0v, we, v);
        h1v = f4fma(h1v, wo, v);
      }
      H0[mi] = h0v; H1[mi] = h1v;
    }
#pragma unroll
    for (int rr2 = 0; rr2 < 2; ++rr2) {
      int r = 2 * (prs - 1) + rr2;
      float4 aee = f4z(), aeo = f4z(), aoe = f4z(), aoo = f4z();
#pragma unroll
      for (int dm = 0; dm < 4; ++dm) {
        float gye = c_g0[2 * dm + 1];
        float gyo = c_g0[2 * dm];
        aee = f4fma(aee, gye, H0[rr2 + dm]);
        aeo = f4fma(aeo, gye, H1[rr2 + dm]);
        aoe = f4fma(aoe, gyo, H0[rr2 + dm]);
        aoo = f4fma(aoo, gyo, H1[rr2 + dm]);
      }
      int y = 2 * r, xx = 2 * q;
      float* ob = out + (((size_t)(b * 128 + y)) * 128 + xx) * 64 + (c4 << 2);
      *(float4*)(ob)              = aee;
      *(float4*)(ob + 64)         = aeo;
      *(float4*)(ob + 8192)       = aoe;
      *(float4*)(ob + 8192 + 64)  = aoo;
    }
    __syncthreads();
    ++prs;
  }
}

extern "C" void kernel_launch(void* const* d_in, const int* in_sizes, int n_in,
                              void* d_out, int out_size, void* d_ws, size_t ws_size,
                              hipStream_t stream) {
  (void)in_sizes; (void)n_in; (void)out_size;
  const float* x  = (const float*)d_in[0];
  const float* w1 = (const float*)d_in[1];
  const float* w2 = (const float*)d_in[2];
  const float* w3 = (const float*)d_in[3];
  const float* w4 = (const float*)d_in[4];
  float* out = (float*)d_out;
  float* ws  = (float*)d_ws;

  // Workspace layout (floats):
  //   [0,        8388608)  ll1
  //   [8388608, 16777216)  subs (4 x 2097152)
  //   [16777216,25165824)  eout (4 x 2097152)
  //   [25165824,41943040)  t1 (dwt1 intermediate, exactly 16777216 floats),
  //                        dead after k_dwt1v; then overwritten by wt.
  float* ll1  = ws;
  float* subs = ws + 8388608;
  float* eout = ws + 16777216;
  float* wt   = ws + 25165824;
  int use_wt = (ws_size >= (size_t)41943040 * 4) ? 1 : 0;
  // t1 shares the wt region when available (transpose runs after dwt1v);
  // fallback: d_out (dead until invfinal).
  float* t1 = use_wt ? (ws + 25165824) : out;

  k_dwt1h<<<16384, 256, 0, stream>>>(x, t1);
  k_dwt1v<<<8192, 256, 0, stream>>>(t1, ll1);
  if (use_wt) k_transpose<<<4096, 256, 0, stream>>>(w1, w2, w3, w4, wt);
  k_dwt2<<<512, 256, 0, stream>>>(ll1, subs);
  k_einsum<<<dim3(1024, 4), 256, 0, stream>>>(subs, w1, w2, w3, w4, wt, eout, use_wt);
  k_invfinal<<<512, 256, 0, stream>>>(eout, out);
}